// Round 7
// baseline (567.213 us; speedup 1.0000x reference)
//
#include <hip/hip_runtime.h>

#define DHW   192
#define DHW2  (DHW*DHW)
#define ZCH   8
#define NT    256
#define RY    20          // y-tile 16 + halo 2 each side
#define RXW   72          // x-tile 64 + halo 4 each side (float4-aligned)
#define SLICE (RY*RXW)    // 1440
#define NF4   (SLICE/4)   // 360
#define ROWF4 (RXW/4)     // 18

// LDS-only drain barrier (verified neutral-or-better vs __syncthreads in R5):
// stores and prefetch loads stay in flight across z-steps.
__device__ __forceinline__ void soft_barrier() {
    asm volatile("s_waitcnt lgkmcnt(0)" ::: "memory");
    __builtin_amdgcn_s_barrier();
    asm volatile("" ::: "memory");
}

__global__ __launch_bounds__(NT, 3)
void mind3d_kernel(const float* __restrict__ img, float* __restrict__ out)
{
    __shared__ __align__(16) float ring[4][SLICE];   // 23 KB, 4-deep z-ring

    const int lane = threadIdx.x;          // 0..63
    const int wid  = threadIdx.y;          // 0..3
    const int tid  = wid*64 + lane;

    const int xq   = lane & 15;            // x-quad: 4 consecutive x per thread
    const int yrow = wid*4 + (lane >> 4);  // 0..15: one output row per thread

    const int x0 = blockIdx.x * 64;
    const int y0 = blockIdx.y * 16;
    const int zi = blockIdx.z;
    const int nzc = DHW / ZCH;             // 24
    const int b  = zi / nzc;
    const int z0 = (zi - b*nzc) * ZCH;

    const float* imgb = img + (size_t)b * ((size_t)DHW * DHW2);

    const float a1 = 0.01831563889245986f;     // exp(-1/sigma^2)
    const float n1 = 1.0f/(1.0f + 2.0f*a1);
    const float norm3 = n1*n1*n1;

    const int bx  = x0 + xq*4;             // outputs bx..bx+3
    const int gyo = y0 + yrow;             // output row

    // x-conv tap coefficients with conv zero-pad folded in (per output j)
    const float cl0 = (bx == 0)         ? 0.f : a1;
    const float cr3 = (bx + 3 == DHW-1) ? 0.f : a1;
    const float cl[4] = {cl0, a1, a1, a1};
    const float cr[4] = {a1, a1, a1, cr3};
    // y-conv tap coefficients with conv zero-pad folded in
    const float myA = (gyo == 0)     ? 0.f : a1;
    const float myC = (gyo == DHW-1) ? 0.f : a1;

    // ---- staging coords (identical to verified R4/R5) ----
    const int r0  = tid / ROWF4, c0i = tid - r0*ROWF4;
    const int gy0s = y0 - 2 + r0, gx0s = x0 - 4 + (c0i << 2);
    const bool in0 = ((unsigned)gy0s < (unsigned)DHW) && ((unsigned)gx0s <= (unsigned)(DHW-4));
    const int t2  = tid + NT;
    const bool g2 = (t2 < NF4);
    const int r1  = t2 / ROWF4, c1i = t2 - r1*ROWF4;
    const int gy1s = y0 - 2 + r1, gx1s = x0 - 4 + (c1i << 2);
    const bool in1 = g2 && ((unsigned)gy1s < (unsigned)DHW) && ((unsigned)gx1s <= (unsigned)(DHW-4));

    float4 sv0, sv1;   // in-flight staged slice (issue early, write late)
    auto issue = [&](int z) {
        sv0 = float4{0.f,0.f,0.f,0.f};
        sv1 = float4{0.f,0.f,0.f,0.f};
        if ((unsigned)z < (unsigned)DHW) {
            const float* sp = imgb + (size_t)z * DHW2;
            if (in0) sv0 = *(const float4*)(sp + (size_t)gy0s*DHW + gx0s);
            if (in1) sv1 = *(const float4*)(sp + (size_t)gy1s*DHW + gx1s);
        }
    };
    auto commit = [&](int z) {
        float4* dst = (float4*)ring[(z + 8) & 3];
        dst[tid] = sv0;
        if (g2) dst[t2] = sv1;
    };

    // z-state per output x (j=0..3): S(z-1), S(z), ch0 carry
    float zm[4][6], zc[4][6], zS0[4];
    #pragma unroll
    for (int j = 0; j < 4; ++j) {
        zS0[j] = 0.f;
        #pragma unroll
        for (int c = 0; c < 6; ++c) { zm[j][c] = 0.f; zc[j][c] = 0.f; }
    }

    issue(z0-2); commit(z0-2);
    issue(z0-1); commit(z0-1);
    issue(z0);   commit(z0);
    issue(z0+1);
    soft_barrier();

    const int qb = 1 + xq;   // float4 index of this thread's base quad in a row

    for (int zs = z0 - 1; zs <= z0 + ZCH; ++zs) {
        if (zs + 2 <= z0 + ZCH + 1) commit(zs + 2);
        if (zs + 3 <= z0 + ZCH + 1) issue(zs + 3);

        const bool zok  = ((unsigned)zs < (unsigned)DHW);
        const bool warm = (zs == z0 - 1);
        const float4* c4 = (const float4*)ring[(zs + 8) & 3];  // center slice
        const float4* p4 = (const float4*)ring[(zs + 9) & 3];  // z+1 slice
        const float4* m4 = (const float4*)ring[(zs + 7) & 3];  // z-1 (warm only)

        // w[0..7] = cols bx-2 .. bx+5 of ring row r
        auto ld8 = [&](const float4* s4, int r, float* w) {
            float4 A = s4[r*ROWF4 + qb - 1];
            float4 B = s4[r*ROWF4 + qb];
            float4 C = s4[r*ROWF4 + qb + 1];
            w[0]=A.z; w[1]=A.w; w[2]=B.x; w[3]=B.y;
            w[4]=B.z; w[5]=B.w; w[6]=C.x; w[7]=C.y;
        };

        float SS[6][4];    // y-conv(x-conv(E)) accumulators, ch x j
        #pragma unroll
        for (int c = 0; c < 6; ++c)
            #pragma unroll
            for (int j = 0; j < 4; ++j) SS[c][j] = 0.f;

        // one T-row: E at x = bx-1+i (i=0..5) -> x-conv -> accumulate with cy
        auto dorow = [&](const float* RA, const float* RB, const float* RC,
                         const float* P, float cy) {
            float q[7];
            #pragma unroll
            for (int i = 0; i < 7; ++i) { float d = RB[i+1]-RB[i]; q[i] = d*d; }
            float E0[6], E2[6], E3[6];
            #pragma unroll
            for (int i = 0; i < 6; ++i) {
                float e;
                e = P[i+1]  - RB[i+1]; E0[i] = e*e;   // +z
                e = RC[i+1] - RB[i+1]; E2[i] = e*e;   // +y
                e = RA[i+1] - RB[i+1]; E3[i] = e*e;   // -y
            }
            #pragma unroll
            for (int j = 0; j < 4; ++j) {
                float t;
                t = cl[j]*E0[j] + (cr[j]*E0[j+2] + E0[j+1]); SS[0][j] += cy*t;
                t = cl[j]*E2[j] + (cr[j]*E2[j+2] + E2[j+1]); SS[2][j] += cy*t;
                t = cl[j]*E3[j] + (cr[j]*E3[j+2] + E3[j+1]); SS[3][j] += cy*t;
                t = cl[j]*q[j+1] + (cr[j]*q[j+3] + q[j+2]);  SS[4][j] += cy*t;   // +x
                t = cl[j]*q[j]   + (cr[j]*q[j+2] + q[j+1]);  SS[5][j] += cy*t;   // -x
            }
        };
        auto dorow1 = [&](const float* RB, const float* PM, float cy) {  // -z, warm
            float E1[6];
            #pragma unroll
            for (int i = 0; i < 6; ++i) { float e = PM[i+1]-RB[i+1]; E1[i] = e*e; }
            #pragma unroll
            for (int j = 0; j < 4; ++j) {
                float t = cl[j]*E1[j] + (cr[j]*E1[j+2] + E1[j+1]);
                SS[1][j] += cy*t;
            }
        };

        // T rows gyo-1, gyo, gyo+1 (ring rows: global g -> g - y0 + 2)
        float L0[8],L1[8],L2[8],L3[8],L4[8],P[8];
        ld8(c4, yrow+0, L0);
        ld8(c4, yrow+1, L1);
        ld8(c4, yrow+2, L2);
        ld8(p4, yrow+1, P);
        dorow(L0, L1, L2, P, myA);
        if (warm) { float PM[8]; ld8(m4, yrow+1, PM); dorow1(L1, PM, myA); }
        ld8(c4, yrow+3, L3);
        ld8(p4, yrow+2, P);
        dorow(L1, L2, L3, P, 1.f);
        if (warm) { float PM[8]; ld8(m4, yrow+2, PM); dorow1(L2, PM, 1.f); }
        ld8(c4, yrow+4, L4);
        ld8(p4, yrow+3, P);
        dorow(L2, L3, L4, P, myC);
        if (warm) { float PM[8]; ld8(m4, yrow+3, PM); dorow1(L3, PM, myC); }

        const int zcout = zs - 1;
        const bool emitz = (zcout >= z0);
        float o[6][4];
        #pragma unroll
        for (int j = 0; j < 4; ++j) {
            float s0 = SS[0][j];                      // raw: feeds ch1 carry
            float s1 = warm ? SS[1][j] : (zok ? zS0[j] : 0.f);
            zS0[j] = s0;
            float s0st = zok ? s0 : 0.f;              // ch0's own state
            float sp[6] = {s0st, s1, SS[2][j], SS[3][j], SS[4][j], SS[5][j]};

            if (emitz) {
                float dp[6], sum = 0.f;
                #pragma unroll
                for (int c = 0; c < 6; ++c) {
                    dp[c] = norm3 * (a1*(zm[j][c] + sp[c]) + zc[j][c]);
                    sum += dp[c];
                }
                float inv = 1.0f / (sum * (1.0f/6.0f) + 1e-8f);
                float num[6], nsum = 0.f;
                #pragma unroll
                for (int c = 0; c < 6; ++c) { num[c] = __expf(-dp[c]*inv); nsum += num[c]; }
                float rs = 1.0f / (nsum + 1e-8f);
                #pragma unroll
                for (int c = 0; c < 6; ++c) o[c][j] = num[c]*rs;
            }
            #pragma unroll
            for (int c = 0; c < 6; ++c) { zm[j][c] = zc[j][c]; zc[j][c] = sp[c]; }
        }
        if (emitz) {
            size_t base = ((size_t)(6*b)*DHW + zcout)*(size_t)DHW2
                        + (size_t)gyo*DHW + (size_t)bx;
            #pragma unroll
            for (int c = 0; c < 6; ++c) {
                float4 v = {o[c][0], o[c][1], o[c][2], o[c][3]};
                *(float4*)(&out[base + (size_t)c*((size_t)DHW*DHW2)]) = v;
            }
        }
        soft_barrier();
    }
}

extern "C" void kernel_launch(void* const* d_in, const int* in_sizes, int n_in,
                              void* d_out, int out_size, void* d_ws, size_t ws_size,
                              hipStream_t stream)
{
    const float* img = (const float*)d_in[0];
    float* out = (float*)d_out;
    dim3 block(64, 4, 1);
    dim3 grid(DHW/64, DHW/16, 2*(DHW/ZCH));   // 3 x 12 x 48 = 1728 blocks
    hipLaunchKernelGGL(mind3d_kernel, grid, block, 0, stream, img, out);
}